// Round 1
// 531.990 us; speedup vs baseline: 1.0133x; 1.0133x over previous
//
#include <hip/hip_runtime.h>
#include <hip/hip_bf16.h>

#define N_NODES 20000
#define N_FEAT  128
#define EIG     32
#define HID     64
#define N_EDGES 640000
#define M_ROWS  (N_NODES * N_FEAT)   /* 2,560,000 */
#define K_DROP  256000               /* int(M*0.1) */
#define NBINS   16384
#define LIST_CAP 4096
#define NTILES  (M_ROWS / 16)        /* 160,000 wave-tiles of 16 rows */
#define NBLK    2560

#define POSS_BYTES ((size_t)M_ROWS * 4)
#define HIST_BYTES (NBINS * 4)
#define META_WORDS 16
/* meta: [0]=bin B, [1]=c_before, [2]=threshold key T, [3]=cutoff index, [7]=collect count */

typedef __attribute__((ext_vector_type(8))) short short8;   // 8 x bf16 (4 VGPRs)
typedef __attribute__((ext_vector_type(4))) float floatx4;  // MFMA C/D

__device__ __forceinline__ short f2bf(float f) {
  unsigned u = __float_as_uint(f);
  unsigned r = u + 0x7fffu + ((u >> 16) & 1u);   // RNE
  return (short)(r >> 16);
}

// packed f32x2 -> bf16x2 (v_cvt_pk_bf16_f32)
__device__ __forceinline__ short2 f2bf2(float x, float y) {
  float2 f; f.x = x; f.y = y;
  __hip_bfloat162 h = __float22bfloat162_rn(f);
  union { __hip_bfloat162 h2; short2 s2; } u;
  u.h2 = h;
  return u.s2;
}

__device__ __forceinline__ int bin_of(float ps) {
  int b = (int)(ps * (float)NBINS);
  if (b > NBINS - 1) b = NBINS - 1;
  if (b < 0) b = 0;
  return b;
}

// Layer1 via MFMA 16x16x32 bf16 (K == EIG). Layer2 reduced to a single
// logit DIFFERENCE (poss depends only on l1-l0), shuffle-reduced.
// Epilogue collapsed algebraically:
//   poss = sigmoid(z1-z0) = A*Lx / (A*Lx + B*Ly),
//   t = e^(l1-l0), A = t+eps*(1+t), B = 1+eps*(1+t), Lx=-ln(ux), Ly=-ln(uy)
// (exact rewrite of softmax->log(+eps)->gumbel->softmax; log base cancels).
// This round: register double-buffer prefetch of next tile's eig float4s AND
// the uni float2 (previously a dependent load in the epilogue tail).
__global__ __launch_bounds__(256) void poss_kernel(
    const float* __restrict__ eig, const float* __restrict__ uni,
    const float* __restrict__ W1, const float* __restrict__ b1,
    const float* __restrict__ W2, const float* __restrict__ b2,
    float* __restrict__ poss, unsigned* __restrict__ hist)
{
  const int wave = threadIdx.x >> 6;
  const int lane = threadIdx.x & 63;
  const int col  = lane & 15;
  const int quad = lane >> 4;
  const int STR  = NBLK * 4;

  // B fragments for W1 (loaded once per wave, reused over grid-stride loop).
  short8 bfrag[4];
  #pragma unroll
  for (int t = 0; t < 4; ++t)
    #pragma unroll
    for (int j = 0; j < 8; ++j)
      bfrag[t][j] = f2bf(W1[(quad * 8 + j) * HID + 16 * t + col]);

  // per-lane epilogue constants: n = 16t + col ; only the W2 column DIFF matters
  float b1v[4], wd[4];
  #pragma unroll
  for (int t = 0; t < 4; ++t) {
    int n = 16 * t + col;
    b1v[t] = b1[n];
    wd[t] = W2[2 * n + 1] - W2[2 * n + 0];
  }
  const float bd = b2[1] - b2[0];

  const bool epi = (col < 4);                // 16 lanes/wave finish rows
  const int  epirow = quad * 4 + col;        // row-within-tile for epilogue lanes

  int tile = blockIdx.x * 4 + wave;
  float4 v0 = {0,0,0,0}, v1 = {0,0,0,0};
  float2 u0 = {0.5f, 0.5f};
  if (tile < NTILES) {
    const float4* pa = (const float4*)(eig + (size_t)(tile * 16 + col) * EIG + quad * 8);
    v0 = pa[0]; v1 = pa[1];
    if (epi) u0 = *(const float2*)(uni + (size_t)(tile * 16 + epirow) * 2);
  }

  for (; tile < NTILES; tile += STR) {
    // ---- prefetch next iteration's loads (issued before any compute) ----
    const int nxt = tile + STR;
    float4 n0 = {0,0,0,0}, n1 = {0,0,0,0};
    float2 nu = {0.5f, 0.5f};
    if (nxt < NTILES) {
      const float4* pn = (const float4*)(eig + (size_t)(nxt * 16 + col) * EIG + quad * 8);
      n0 = pn[0]; n1 = pn[1];
      if (epi) nu = *(const float2*)(uni + (size_t)(nxt * 16 + epirow) * 2);
    }

    // ---- compute current tile ----
    const int rowbase = tile * 16;
    union { short8 v; short2 h[4]; } au;
    au.h[0] = f2bf2(v0.x, v0.y);
    au.h[1] = f2bf2(v0.z, v0.w);
    au.h[2] = f2bf2(v1.x, v1.y);
    au.h[3] = f2bf2(v1.z, v1.w);

    floatx4 c[4];
    const floatx4 z = {0.f, 0.f, 0.f, 0.f};
    #pragma unroll
    for (int t = 0; t < 4; ++t)
      c[t] = __builtin_amdgcn_mfma_f32_16x16x32_bf16(au.v, bfrag[t], z, 0, 0, 0);

    // layer2 diff partials: lane holds h[row=quad*4+r][n=16t+col] in c[t][r]
    float pd[4] = {0, 0, 0, 0};
    #pragma unroll
    for (int t = 0; t < 4; ++t)
      #pragma unroll
      for (int r = 0; r < 4; ++r) {
        float h = fmaxf(c[t][r] + b1v[t], 0.0f);
        pd[r] = fmaf(h, wd[t], pd[r]);
      }

    // reduce over the 16 lanes of each quad-group (n-dimension)
    #pragma unroll
    for (int s = 1; s < 16; s <<= 1)
      #pragma unroll
      for (int r = 0; r < 4; ++r)
        pd[r] += __shfl_xor(pd[r], s, 64);

    // epilogue: 16 lanes/wave (col<4) each finish one row; uni was prefetched
    if (epi) {
      int r = col;
      float ldiff = ((r == 0) ? pd[0] : (r == 1) ? pd[1] : (r == 2) ? pd[2] : pd[3]) + bd;
      int row = rowbase + epirow;

      float t = __expf(ldiff);              // e^(l1-l0)
      float e1t = 1e-8f * (1.0f + t);
      float A = t + e1t;                    // ∝ s1+eps
      float B = 1.0f + e1t;                 // ∝ s0+eps
      float Lx = -__logf(u0.x);             // -ln(ux) > 0
      float Ly = -__logf(u0.y);
      float num = A * Lx;
      float ps = __fdividef(num, num + B * Ly);
      ps = fminf(fmaxf(ps, 1e-6f), 1.0f);
      poss[row] = ps;
      atomicAdd(&hist[bin_of(ps)], 1u);
    }

    v0 = n0; v1 = n1; u0 = nu;
  }
}

// find bin B such that cum_excl(B) < K_DROP <= cum_incl(B); store B, cum_excl.
// Parallel: 256 chunk sums -> Hillis-Steele inclusive scan -> unique thread
// identifies the boundary chunk -> its 64 bins staged to LDS -> short LDS scan.
__global__ void scan_kernel(const unsigned* __restrict__ hist, unsigned* __restrict__ meta)
{
  __shared__ unsigned psum[256];
  __shared__ unsigned chunkbins[64];
  __shared__ unsigned selc, selcum;
  int t = threadIdx.x;
  unsigned s = 0;
  #pragma unroll 4
  for (int i = 0; i < NBINS / 256; ++i) s += hist[t * (NBINS / 256) + i];
  psum[t] = s;
  __syncthreads();
  // inclusive prefix scan over 256 entries
  for (int off = 1; off < 256; off <<= 1) {
    unsigned add = (t >= off) ? psum[t - off] : 0u;
    __syncthreads();
    psum[t] += add;
    __syncthreads();
  }
  unsigned incl = psum[t];
  unsigned excl = incl - s;
  if (excl < K_DROP && K_DROP <= incl) { selc = (unsigned)t; selcum = excl; }
  __syncthreads();
  unsigned c = selc;
  if (t < NBINS / 256) chunkbins[t] = hist[c * (NBINS / 256) + t];
  __syncthreads();
  if (t == 0) {
    unsigned cum = selcum;
    int b = (int)c * (NBINS / 256);
    for (int i = 0; i < NBINS / 256; ++i) {
      unsigned h = chunkbins[i];
      if (cum + h >= K_DROP) { meta[0] = (unsigned)(b + i); meta[1] = cum; break; }
      cum += h;
    }
  }
}

// float4-vectorized poss scan for boundary-bin members; ALSO carries the
// poss-independent edge_index/edge_weight copy (was in finalize).
__global__ __launch_bounds__(256) void collect_kernel(
    const float* __restrict__ poss, unsigned* __restrict__ meta,
    unsigned* __restrict__ list,
    const int* __restrict__ ei, const float* __restrict__ ew,
    float* __restrict__ out)
{
  int i = blockIdx.x * 256 + threadIdx.x;
  if (i < M_ROWS / 4) {
    float4 p = ((const float4*)poss)[i];
    int B = (int)meta[0];
    float pp[4] = {p.x, p.y, p.z, p.w};
    #pragma unroll
    for (int j = 0; j < 4; ++j) {
      if (bin_of(pp[j]) == B) {
        unsigned q = atomicAdd(&meta[7], 1u);
        if (q < LIST_CAP) list[q] = (unsigned)(4 * i + j);
      }
    }
  } else {
    int j = (i - M_ROWS / 4) * 4;   // float index in edge region of out
    if (j < 2 * N_EDGES) {
      int4 e = *(const int4*)(ei + j);
      *(float4*)(out + M_ROWS + j) =
          make_float4((float)e.x, (float)e.y, (float)e.z, (float)e.w);
    } else {
      int k = j - 2 * N_EDGES;
      *(float4*)(out + M_ROWS + j) = *(const float4*)(ew + k);
    }
  }
}

// exact rank within the boundary bin, tie-break by ascending index (matches top_k)
__global__ void rank_kernel(const float* __restrict__ poss,
                            const unsigned* __restrict__ list,
                            unsigned* __restrict__ meta)
{
  __shared__ unsigned sk[LIST_CAP];
  __shared__ unsigned si[LIST_CAP];
  unsigned n = meta[7];
  if (n > LIST_CAP) n = LIST_CAP;
  unsigned target = K_DROP - meta[1] - 1;   // 0-indexed rank inside this bin
  int t = threadIdx.x;
  for (unsigned i = t; i < n; i += 256) {
    unsigned ix = list[i];
    si[i] = ix;
    sk[i] = __float_as_uint(poss[ix]);   // poss>0 so uint order == float order
  }
  __syncthreads();
  for (unsigned el = t; el < n; el += 256) {
    unsigned k = sk[el], ix = si[el];
    unsigned r = 0;
    for (unsigned j = 0; j < n; ++j)
      r += (sk[j] < k) || (sk[j] == k && si[j] < ix);
    if (r == target) { meta[2] = k; meta[3] = ix; }
  }
}

// x region only (edge region handled by collect_kernel), float4-vectorized.
__global__ __launch_bounds__(256) void finalize_kernel(
    const float* __restrict__ x, const float* __restrict__ poss,
    const unsigned* __restrict__ meta, float* __restrict__ out)
{
  int i = blockIdx.x * 256 + threadIdx.x;
  if (i >= M_ROWS / 4) return;
  unsigned T = meta[2], cut = meta[3];
  float4 xv = ((const float4*)x)[i];
  float4 pv = ((const float4*)poss)[i];
  float xx[4] = {xv.x, xv.y, xv.z, xv.w};
  float pp[4] = {pv.x, pv.y, pv.z, pv.w};
  float o[4];
  #pragma unroll
  for (int j = 0; j < 4; ++j) {
    unsigned k = __float_as_uint(pp[j]);
    unsigned idx = (unsigned)(4 * i + j);
    bool sel = (k < T) || (k == T && idx <= cut);
    o[j] = sel ? xx[j] * pp[j] : xx[j];
  }
  ((float4*)out)[i] = make_float4(o[0], o[1], o[2], o[3]);
}

extern "C" void kernel_launch(void* const* d_in, const int* in_sizes, int n_in,
                              void* d_out, int out_size, void* d_ws, size_t ws_size,
                              hipStream_t stream)
{
  const float* x   = (const float*)d_in[0];
  const int*   ei  = (const int*)d_in[1];
  const float* ew  = (const float*)d_in[2];
  const float* eig = (const float*)d_in[3];
  const float* uni = (const float*)d_in[4];
  const float* W1  = (const float*)d_in[5];
  const float* b1  = (const float*)d_in[6];
  const float* W2  = (const float*)d_in[7];
  const float* b2  = (const float*)d_in[8];
  float* out = (float*)d_out;

  char* ws = (char*)d_ws;
  float*    poss = (float*)ws;
  unsigned* hist = (unsigned*)(ws + POSS_BYTES);
  unsigned* meta = (unsigned*)(ws + POSS_BYTES + HIST_BYTES);
  unsigned* list = (unsigned*)(ws + POSS_BYTES + HIST_BYTES + META_WORDS * 4);

  hipMemsetAsync(hist, 0, HIST_BYTES + META_WORDS * 4 + LIST_CAP * 4, stream);
  poss_kernel<<<NBLK, 256, 0, stream>>>(eig, uni, W1, b1, W2, b2, poss, hist);
  scan_kernel<<<1, 256, 0, stream>>>(hist, meta);
  // poss part: M_ROWS/1024 = 2500 blocks; edge part: 3*N_EDGES/1024 = 1875 blocks
  collect_kernel<<<2500 + 1875, 256, 0, stream>>>(poss, meta, list, ei, ew, out);
  rank_kernel<<<1, 256, 0, stream>>>(poss, list, meta);
  finalize_kernel<<<2500, 256, 0, stream>>>(x, poss, meta, out);
}

// Round 2
// 531.730 us; speedup vs baseline: 1.0138x; 1.0005x over previous
//
#include <hip/hip_runtime.h>
#include <hip/hip_bf16.h>

#define N_NODES 20000
#define N_FEAT  128
#define EIG     32
#define HID     64
#define N_EDGES 640000
#define M_ROWS  (N_NODES * N_FEAT)   /* 2,560,000 */
#define K_DROP  256000               /* int(M*0.1) */
#define NBINS   16384
#define LIST_CAP 4096
#define NTILES  (M_ROWS / 16)        /* 160,000 wave-tiles of 16 rows */
#define NBLK    2560

#define POSS_BYTES ((size_t)M_ROWS * 4)
#define HIST_BYTES (NBINS * 4)
#define META_WORDS 16
/* meta: [0]=bin B, [1]=c_before, [2]=threshold key T, [3]=cutoff index, [7]=collect count */

typedef __attribute__((ext_vector_type(8))) short short8;   // 8 x bf16 (4 VGPRs)
typedef __attribute__((ext_vector_type(4))) float floatx4;  // MFMA C/D

__device__ __forceinline__ short f2bf(float f) {
  unsigned u = __float_as_uint(f);
  unsigned r = u + 0x7fffu + ((u >> 16) & 1u);   // RNE
  return (short)(r >> 16);
}

// packed f32x2 -> bf16x2 (v_cvt_pk_bf16_f32)
__device__ __forceinline__ short2 f2bf2(float x, float y) {
  float2 f; f.x = x; f.y = y;
  __hip_bfloat162 h = __float22bfloat162_rn(f);
  union { __hip_bfloat162 h2; short2 s2; } u;
  u.h2 = h;
  return u.s2;
}

__device__ __forceinline__ int bin_of(float ps) {
  int b = (int)(ps * (float)NBINS);
  if (b > NBINS - 1) b = NBINS - 1;
  if (b < 0) b = 0;
  return b;
}

// Layer1 via MFMA 16x16x32 bf16 (K == EIG). Layer2 reduced to a single
// logit DIFFERENCE (poss depends only on l1-l0), shuffle-reduced.
// Epilogue collapsed algebraically:
//   poss = sigmoid(z1-z0) = A*Lx / (A*Lx + B*Ly),
//   t = e^(l1-l0), A = t+eps*(1+t), B = 1+eps*(1+t), Lx=-ln(ux), Ly=-ln(uy)
// (exact rewrite of softmax->log(+eps)->gumbel->softmax; log base cancels).
// Register double-buffer prefetch of next tile's eig float4s and uni float2.
__global__ __launch_bounds__(256) void poss_kernel(
    const float* __restrict__ eig, const float* __restrict__ uni,
    const float* __restrict__ W1, const float* __restrict__ b1,
    const float* __restrict__ W2, const float* __restrict__ b2,
    float* __restrict__ poss, unsigned* __restrict__ hist)
{
  const int wave = threadIdx.x >> 6;
  const int lane = threadIdx.x & 63;
  const int col  = lane & 15;
  const int quad = lane >> 4;
  const int STR  = NBLK * 4;

  // B fragments for W1 (loaded once per wave, reused over grid-stride loop).
  short8 bfrag[4];
  #pragma unroll
  for (int t = 0; t < 4; ++t)
    #pragma unroll
    for (int j = 0; j < 8; ++j)
      bfrag[t][j] = f2bf(W1[(quad * 8 + j) * HID + 16 * t + col]);

  // per-lane epilogue constants: n = 16t + col ; only the W2 column DIFF matters
  float b1v[4], wd[4];
  #pragma unroll
  for (int t = 0; t < 4; ++t) {
    int n = 16 * t + col;
    b1v[t] = b1[n];
    wd[t] = W2[2 * n + 1] - W2[2 * n + 0];
  }
  const float bd = b2[1] - b2[0];

  const bool epi = (col < 4);                // 16 lanes/wave finish rows
  const int  epirow = quad * 4 + col;        // row-within-tile for epilogue lanes

  int tile = blockIdx.x * 4 + wave;
  float4 v0 = {0,0,0,0}, v1 = {0,0,0,0};
  float2 u0 = {0.5f, 0.5f};
  if (tile < NTILES) {
    const float4* pa = (const float4*)(eig + (size_t)(tile * 16 + col) * EIG + quad * 8);
    v0 = pa[0]; v1 = pa[1];
    if (epi) u0 = *(const float2*)(uni + (size_t)(tile * 16 + epirow) * 2);
  }

  for (; tile < NTILES; tile += STR) {
    // ---- prefetch next iteration's loads (issued before any compute) ----
    const int nxt = tile + STR;
    float4 n0 = {0,0,0,0}, n1 = {0,0,0,0};
    float2 nu = {0.5f, 0.5f};
    if (nxt < NTILES) {
      const float4* pn = (const float4*)(eig + (size_t)(nxt * 16 + col) * EIG + quad * 8);
      n0 = pn[0]; n1 = pn[1];
      if (epi) nu = *(const float2*)(uni + (size_t)(nxt * 16 + epirow) * 2);
    }

    // ---- compute current tile ----
    const int rowbase = tile * 16;
    union { short8 v; short2 h[4]; } au;
    au.h[0] = f2bf2(v0.x, v0.y);
    au.h[1] = f2bf2(v0.z, v0.w);
    au.h[2] = f2bf2(v1.x, v1.y);
    au.h[3] = f2bf2(v1.z, v1.w);

    floatx4 c[4];
    const floatx4 z = {0.f, 0.f, 0.f, 0.f};
    #pragma unroll
    for (int t = 0; t < 4; ++t)
      c[t] = __builtin_amdgcn_mfma_f32_16x16x32_bf16(au.v, bfrag[t], z, 0, 0, 0);

    // layer2 diff partials: lane holds h[row=quad*4+r][n=16t+col] in c[t][r]
    float pd[4] = {0, 0, 0, 0};
    #pragma unroll
    for (int t = 0; t < 4; ++t)
      #pragma unroll
      for (int r = 0; r < 4; ++r) {
        float h = fmaxf(c[t][r] + b1v[t], 0.0f);
        pd[r] = fmaf(h, wd[t], pd[r]);
      }

    // reduce over the 16 lanes of each quad-group (n-dimension)
    #pragma unroll
    for (int s = 1; s < 16; s <<= 1)
      #pragma unroll
      for (int r = 0; r < 4; ++r)
        pd[r] += __shfl_xor(pd[r], s, 64);

    // epilogue: 16 lanes/wave (col<4) each finish one row; uni was prefetched
    if (epi) {
      int r = col;
      float ldiff = ((r == 0) ? pd[0] : (r == 1) ? pd[1] : (r == 2) ? pd[2] : pd[3]) + bd;
      int row = rowbase + epirow;

      float t = __expf(ldiff);              // e^(l1-l0)
      float e1t = 1e-8f * (1.0f + t);
      float A = t + e1t;                    // ∝ s1+eps
      float B = 1.0f + e1t;                 // ∝ s0+eps
      float Lx = -__logf(u0.x);             // -ln(ux) > 0
      float Ly = -__logf(u0.y);
      float num = A * Lx;
      float ps = __fdividef(num, num + B * Ly);
      ps = fminf(fmaxf(ps, 1e-6f), 1.0f);
      poss[row] = ps;
      atomicAdd(&hist[bin_of(ps)], 1u);
    }

    v0 = n0; v1 = n1; u0 = nu;
  }
}

// Block 0: find bin B such that cum_excl(B) < K_DROP <= cum_incl(B); store B,
// cum_excl. Blocks 1..1875: the poss-independent edge_index/edge_weight copy
// (overlaps the serial scan latency with BW work).
__global__ __launch_bounds__(256) void scan_edge_kernel(
    const unsigned* __restrict__ hist, unsigned* __restrict__ meta,
    const int* __restrict__ ei, const float* __restrict__ ew,
    float* __restrict__ out)
{
  if (blockIdx.x != 0) {
    int j = (blockIdx.x - 1) * 1024 + threadIdx.x * 4;  // float idx in edge region
    if (j < 2 * N_EDGES) {
      int4 e = *(const int4*)(ei + j);
      *(float4*)(out + M_ROWS + j) =
          make_float4((float)e.x, (float)e.y, (float)e.z, (float)e.w);
    } else {
      int k = j - 2 * N_EDGES;
      *(float4*)(out + M_ROWS + j) = *(const float4*)(ew + k);
    }
    return;
  }

  __shared__ unsigned psum[256];
  __shared__ unsigned chunkbins[64];
  __shared__ unsigned selc, selcum;
  int t = threadIdx.x;
  unsigned s = 0;
  #pragma unroll 4
  for (int i = 0; i < NBINS / 256; ++i) s += hist[t * (NBINS / 256) + i];
  psum[t] = s;
  __syncthreads();
  // inclusive prefix scan over 256 entries
  for (int off = 1; off < 256; off <<= 1) {
    unsigned add = (t >= off) ? psum[t - off] : 0u;
    __syncthreads();
    psum[t] += add;
    __syncthreads();
  }
  unsigned incl = psum[t];
  unsigned excl = incl - s;
  if (excl < K_DROP && K_DROP <= incl) { selc = (unsigned)t; selcum = excl; }
  __syncthreads();
  unsigned c = selc;
  if (t < NBINS / 256) chunkbins[t] = hist[c * (NBINS / 256) + t];
  __syncthreads();
  if (t == 0) {
    unsigned cum = selcum;
    int b = (int)c * (NBINS / 256);
    for (int i = 0; i < NBINS / 256; ++i) {
      unsigned h = chunkbins[i];
      if (cum + h >= K_DROP) { meta[0] = (unsigned)(b + i); meta[1] = cum; break; }
      cum += h;
    }
  }
}

// Fused collect + finalize (single pass over poss + x):
//   bin < B  -> definitely selected  -> out = x * ps
//   bin > B  -> definitely kept      -> out = x
//   bin == B -> provisional out = x, append index to boundary list;
//              rank_fix_kernel rewrites the selected ones afterwards.
__global__ __launch_bounds__(256) void collect_fin_kernel(
    const float* __restrict__ poss, const float* __restrict__ x,
    unsigned* __restrict__ meta, unsigned* __restrict__ list,
    float* __restrict__ out)
{
  int i = blockIdx.x * 256 + threadIdx.x;   // i < M_ROWS/4
  float4 p = ((const float4*)poss)[i];
  float4 xv = ((const float4*)x)[i];
  int B = (int)meta[0];
  float pp[4] = {p.x, p.y, p.z, p.w};
  float xx[4] = {xv.x, xv.y, xv.z, xv.w};
  float o[4];
  #pragma unroll
  for (int j = 0; j < 4; ++j) {
    int b = bin_of(pp[j]);
    o[j] = (b < B) ? xx[j] * pp[j] : xx[j];
    if (b == B) {
      unsigned q = atomicAdd(&meta[7], 1u);
      if (q < LIST_CAP) list[q] = (unsigned)(4 * i + j);
    }
  }
  ((float4*)out)[i] = make_float4(o[0], o[1], o[2], o[3]);
}

// exact rank within the boundary bin, tie-break by ascending index (matches
// top_k), then directly fix up the <=LIST_CAP boundary-bin outputs.
__global__ __launch_bounds__(256) void rank_fix_kernel(
    const float* __restrict__ poss, const float* __restrict__ x,
    const unsigned* __restrict__ list, unsigned* __restrict__ meta,
    float* __restrict__ out)
{
  __shared__ unsigned sk[LIST_CAP];
  __shared__ unsigned si[LIST_CAP];
  __shared__ unsigned sT, sCut;
  unsigned n = meta[7];
  if (n > LIST_CAP) n = LIST_CAP;
  unsigned target = K_DROP - meta[1] - 1;   // 0-indexed rank inside this bin
  int t = threadIdx.x;
  for (unsigned i = t; i < n; i += 256) {
    unsigned ix = list[i];
    si[i] = ix;
    sk[i] = __float_as_uint(poss[ix]);   // poss>0 so uint order == float order
  }
  __syncthreads();
  for (unsigned el = t; el < n; el += 256) {
    unsigned k = sk[el], ix = si[el];
    unsigned r = 0;
    for (unsigned j = 0; j < n; ++j)
      r += (sk[j] < k) || (sk[j] == k && si[j] < ix);
    if (r == target) { sT = k; sCut = ix; meta[2] = k; meta[3] = ix; }
  }
  __syncthreads();
  unsigned T = sT, cut = sCut;
  for (unsigned i = t; i < n; i += 256) {
    unsigned ix = si[i], k = sk[i];
    bool sel = (k < T) || (k == T && ix <= cut);
    if (sel) out[ix] = x[ix] * __uint_as_float(k);
  }
}

extern "C" void kernel_launch(void* const* d_in, const int* in_sizes, int n_in,
                              void* d_out, int out_size, void* d_ws, size_t ws_size,
                              hipStream_t stream)
{
  const float* x   = (const float*)d_in[0];
  const int*   ei  = (const int*)d_in[1];
  const float* ew  = (const float*)d_in[2];
  const float* eig = (const float*)d_in[3];
  const float* uni = (const float*)d_in[4];
  const float* W1  = (const float*)d_in[5];
  const float* b1  = (const float*)d_in[6];
  const float* W2  = (const float*)d_in[7];
  const float* b2  = (const float*)d_in[8];
  float* out = (float*)d_out;

  char* ws = (char*)d_ws;
  float*    poss = (float*)ws;
  unsigned* hist = (unsigned*)(ws + POSS_BYTES);
  unsigned* meta = (unsigned*)(ws + POSS_BYTES + HIST_BYTES);
  unsigned* list = (unsigned*)(ws + POSS_BYTES + HIST_BYTES + META_WORDS * 4);

  hipMemsetAsync(hist, 0, HIST_BYTES + META_WORDS * 4 + LIST_CAP * 4, stream);
  poss_kernel<<<NBLK, 256, 0, stream>>>(eig, uni, W1, b1, W2, b2, poss, hist);
  // block 0 scans the histogram; 1875 blocks carry the edge copy in parallel
  scan_edge_kernel<<<1876, 256, 0, stream>>>(hist, meta, ei, ew, out);
  collect_fin_kernel<<<M_ROWS / 1024, 256, 0, stream>>>(poss, x, meta, list, out);
  rank_fix_kernel<<<1, 256, 0, stream>>>(poss, x, list, meta, out);
}